// Round 1
// baseline (2475.298 us; speedup 1.0000x reference)
//
#include <hip/hip_runtime.h>

// ---------------------------------------------------------------------------
// MultiHeadSelfAttention: B=2, S=2048, D=1024, H=16, hd=64, fp32 in/out.
//   1. QKV projections (fused 3-way GEMM via grid.z)
//   2. Flash attention (1 q-row per lane, K/V tiles in LDS, online softmax)
//   3. Output projection (same GEMM kernel)
// Round 1: correctness-first fp32 baseline (no fp32 MFMA on CDNA4).
// ---------------------------------------------------------------------------

#define GBM 128
#define GBN 128
#define GBK 8

__global__ __launch_bounds__(256) void gemm_bias_kernel(
    const float* __restrict__ A,
    const float* __restrict__ W0, const float* __restrict__ W1, const float* __restrict__ W2,
    const float* __restrict__ b0, const float* __restrict__ b1, const float* __restrict__ b2,
    float* __restrict__ C0, float* __restrict__ C1, float* __restrict__ C2,
    int M, int N, int Kdim)
{
  const float* W    = (blockIdx.z == 0) ? W0 : (blockIdx.z == 1) ? W1 : W2;
  const float* bias = (blockIdx.z == 0) ? b0 : (blockIdx.z == 1) ? b1 : b2;
  float* C          = (blockIdx.z == 0) ? C0 : (blockIdx.z == 1) ? C1 : C2;

  __shared__ float As[GBK][GBM + 4];  // A^T tile: As[k][m], pad -> stride 132 (16B-aligned, conflict-free)
  __shared__ float Bs[GBK][GBN];      // Bs[k][n]

  const int tid = threadIdx.x;
  const int bm = blockIdx.y * GBM;
  const int bn = blockIdx.x * GBN;
  const int tm = (tid >> 4) << 3;   // 0..120
  const int tn = (tid & 15) << 3;   // 0..120

  // staging indices
  const int arow = tid >> 1;         // 0..127
  const int acol = (tid & 1) << 2;   // 0 or 4
  const int brow = tid >> 5;         // 0..7
  const int bcol = (tid & 31) << 2;  // 0..124

  const float* Aptr = A + (size_t)(bm + arow) * Kdim + acol;
  const float* Wptr = W + (size_t)brow * N + bn + bcol;

  float acc[8][8];
#pragma unroll
  for (int i = 0; i < 8; ++i)
#pragma unroll
    for (int j = 0; j < 8; ++j) acc[i][j] = 0.f;

  for (int k0 = 0; k0 < Kdim; k0 += GBK) {
    const float4 av = *(const float4*)(Aptr + k0);
    const float4 bv = *(const float4*)(Wptr + (size_t)k0 * N);
    __syncthreads();
    As[acol + 0][arow] = av.x;
    As[acol + 1][arow] = av.y;
    As[acol + 2][arow] = av.z;
    As[acol + 3][arow] = av.w;
    *(float4*)&Bs[brow][bcol] = bv;
    __syncthreads();
#pragma unroll
    for (int k = 0; k < GBK; ++k) {
      float a[8], b[8];
      *(float4*)&a[0] = *(const float4*)&As[k][tm];
      *(float4*)&a[4] = *(const float4*)&As[k][tm + 4];
      *(float4*)&b[0] = *(const float4*)&Bs[k][tn];
      *(float4*)&b[4] = *(const float4*)&Bs[k][tn + 4];
#pragma unroll
      for (int i = 0; i < 8; ++i)
#pragma unroll
        for (int j = 0; j < 8; ++j)
          acc[i][j] = fmaf(a[i], b[j], acc[i][j]);
    }
  }

#pragma unroll
  for (int i = 0; i < 8; ++i) {
    float* crow = C + (size_t)(bm + tm + i) * N + bn + tn;
#pragma unroll
    for (int j = 0; j < 8; j += 4) {
      float4 outv;
      outv.x = acc[i][j + 0] + bias[bn + tn + j + 0];
      outv.y = acc[i][j + 1] + bias[bn + tn + j + 1];
      outv.z = acc[i][j + 2] + bias[bn + tn + j + 2];
      outv.w = acc[i][j + 3] + bias[bn + tn + j + 3];
      *(float4*)(crow + j) = outv;
    }
  }
}

// ---------------------------------------------------------------------------
// Flash attention, fp32. One wave per block; lane r owns q-row r of a 64-row
// q-tile (q[64] and o[64] live in registers). K/V staged in LDS in 64-row
// tiles; the kk loop is wave-uniform so all LDS reads broadcast (no bank
// conflicts). Online softmax over 8-key chunks (all reg indices static).
// ---------------------------------------------------------------------------

#define QB 64
#define KB 64
#define HD 64

__global__ __launch_bounds__(64) void flash_attn_kernel(
    const float* __restrict__ Q, const float* __restrict__ K,
    const float* __restrict__ V, float* __restrict__ O,
    int S, int D, int H)
{
  __shared__ float Ks[KB][HD + 4];  // stride 68 floats = 272B, 16B-aligned
  __shared__ float Vs[KB][HD + 4];

  const int bh = blockIdx.x;      // 0 .. B*H-1
  const int b = bh / H;
  const int h = bh - b * H;
  const int qb = blockIdx.y;
  const int r = threadIdx.x;      // 0..63
  const int token = b * S + qb * QB + r;

  const float* qptr = Q + (size_t)token * D + h * HD;

  float q[HD], o[HD];
#pragma unroll
  for (int j = 0; j < HD; j += 4)
    *(float4*)&q[j] = *(const float4*)(qptr + j);
#pragma unroll
  for (int j = 0; j < HD; ++j) o[j] = 0.f;

  float m = -1e30f, l = 0.f;
  const float scale = 0.125f;  // 1/sqrt(64)

  const int kvbase = b * S;

  for (int kb = 0; kb < S; kb += KB) {
    const float* kptr = K + (size_t)(kvbase + kb + r) * D + h * HD;
    const float* vptr = V + (size_t)(kvbase + kb + r) * D + h * HD;
    __syncthreads();
#pragma unroll
    for (int j = 0; j < HD; j += 4) {
      *(float4*)&Ks[r][j] = *(const float4*)(kptr + j);
      *(float4*)&Vs[r][j] = *(const float4*)(vptr + j);
    }
    __syncthreads();

    // process the 64 keys in chunks of 8 (score regs static-indexed)
#pragma unroll 1
    for (int kk0 = 0; kk0 < KB; kk0 += 8) {
      float sv[8];
      float bmax = -1e30f;
#pragma unroll
      for (int u = 0; u < 8; ++u) {
        const float* krow = &Ks[kk0 + u][0];
        float accs = 0.f;
#pragma unroll
        for (int j = 0; j < HD; j += 4) {
          const float4 kv = *(const float4*)(krow + j);
          accs = fmaf(q[j + 0], kv.x, accs);
          accs = fmaf(q[j + 1], kv.y, accs);
          accs = fmaf(q[j + 2], kv.z, accs);
          accs = fmaf(q[j + 3], kv.w, accs);
        }
        sv[u] = accs * scale;
        bmax = fmaxf(bmax, sv[u]);
      }
      const float m_new = fmaxf(m, bmax);
      const float f = __expf(m - m_new);
      l *= f;
#pragma unroll
      for (int j = 0; j < HD; ++j) o[j] *= f;
      m = m_new;
#pragma unroll
      for (int u = 0; u < 8; ++u) {
        const float p = __expf(sv[u] - m);
        l += p;
        const float* vrow = &Vs[kk0 + u][0];
#pragma unroll
        for (int j = 0; j < HD; j += 4) {
          const float4 vv = *(const float4*)(vrow + j);
          o[j + 0] = fmaf(p, vv.x, o[j + 0]);
          o[j + 1] = fmaf(p, vv.y, o[j + 1]);
          o[j + 2] = fmaf(p, vv.z, o[j + 2]);
          o[j + 3] = fmaf(p, vv.w, o[j + 3]);
        }
      }
    }
  }

  const float inv = 1.f / l;
  float* optr = O + (size_t)token * D + h * HD;
#pragma unroll
  for (int j = 0; j < HD; j += 4) {
    float4 ov;
    ov.x = o[j + 0] * inv;
    ov.y = o[j + 1] * inv;
    ov.z = o[j + 2] * inv;
    ov.w = o[j + 3] * inv;
    *(float4*)(optr + j) = ov;
  }
}

// ---------------------------------------------------------------------------

extern "C" void kernel_launch(void* const* d_in, const int* in_sizes, int n_in,
                              void* d_out, int out_size, void* d_ws, size_t ws_size,
                              hipStream_t stream) {
  const float* X  = (const float*)d_in[0];
  const float* Wq = (const float*)d_in[1];
  const float* bq = (const float*)d_in[2];
  const float* Wk = (const float*)d_in[3];
  const float* bk = (const float*)d_in[4];
  const float* Wv = (const float*)d_in[5];
  const float* bv = (const float*)d_in[6];
  const float* Wo = (const float*)d_in[7];
  const float* bo = (const float*)d_in[8];
  float* out = (float*)d_out;

  const int B = 2, S = 2048, D = 1024, H = 16;
  const int M = B * S;  // 4096

  float* Qb = (float*)d_ws;
  float* Kb = Qb + (size_t)M * D;
  float* Vb = Kb + (size_t)M * D;
  float* Cc = Vb + (size_t)M * D;  // attention concat output

  // 1. fused QKV projections
  dim3 gqkv(D / GBN, M / GBM, 3);
  gemm_bias_kernel<<<gqkv, 256, 0, stream>>>(X, Wq, Wk, Wv, bq, bk, bv,
                                             Qb, Kb, Vb, M, D, D);

  // 2. flash attention
  dim3 gattn(B * H, S / QB);
  flash_attn_kernel<<<gattn, 64, 0, stream>>>(Qb, Kb, Vb, Cc, S, D, H);

  // 3. output projection
  dim3 gout(D / GBN, M / GBM, 1);
  gemm_bias_kernel<<<gout, 256, 0, stream>>>(Cc, Wo, Wo, Wo, bo, bo, bo,
                                             out, out, out, M, D, D);
}

// Round 2
// 610.821 us; speedup vs baseline: 4.0524x; 4.0524x over previous
//
#include <hip/hip_runtime.h>

// ---------------------------------------------------------------------------
// MultiHeadSelfAttention: B=2, S=2048, D=1024, H=16, hd=64, fp32 in/out.
//   1. QKV projections (fused 3-way fp32 GEMM, unchanged from R1)
//   2. Flash attention via bf16 MFMA, split-precision QK^T (R2 NEW)
//   3. Output projection (fp32 GEMM, unchanged)
// ---------------------------------------------------------------------------

typedef __attribute__((ext_vector_type(8))) short bf16x8;
typedef __attribute__((ext_vector_type(16))) float f32x16;

__device__ __forceinline__ unsigned short f2bf(float f) {
  unsigned int u = __float_as_uint(f);
  unsigned int r = (u + 0x7FFFu + ((u >> 16) & 1u)) >> 16;  // RNE
  return (unsigned short)r;
}
__device__ __forceinline__ float bf2f(unsigned short s) {
  return __uint_as_float(((unsigned int)s) << 16);
}
__device__ __forceinline__ unsigned int packbf(float a, float b) {
  return (unsigned int)f2bf(a) | ((unsigned int)f2bf(b) << 16);
}

// ---------------------------------------------------------------------------
// fp32 GEMM with bias (unchanged, known-good)
// ---------------------------------------------------------------------------
#define GBM 128
#define GBN 128
#define GBK 8

__global__ __launch_bounds__(256) void gemm_bias_kernel(
    const float* __restrict__ A,
    const float* __restrict__ W0, const float* __restrict__ W1, const float* __restrict__ W2,
    const float* __restrict__ b0, const float* __restrict__ b1, const float* __restrict__ b2,
    float* __restrict__ C0, float* __restrict__ C1, float* __restrict__ C2,
    int M, int N, int Kdim)
{
  const float* W    = (blockIdx.z == 0) ? W0 : (blockIdx.z == 1) ? W1 : W2;
  const float* bias = (blockIdx.z == 0) ? b0 : (blockIdx.z == 1) ? b1 : b2;
  float* C          = (blockIdx.z == 0) ? C0 : (blockIdx.z == 1) ? C1 : C2;

  __shared__ float As[GBK][GBM + 4];
  __shared__ float Bs[GBK][GBN];

  const int tid = threadIdx.x;
  const int bm = blockIdx.y * GBM;
  const int bn = blockIdx.x * GBN;
  const int tm = (tid >> 4) << 3;
  const int tn = (tid & 15) << 3;

  const int arow = tid >> 1;
  const int acol = (tid & 1) << 2;
  const int brow = tid >> 5;
  const int bcol = (tid & 31) << 2;

  const float* Aptr = A + (size_t)(bm + arow) * Kdim + acol;
  const float* Wptr = W + (size_t)brow * N + bn + bcol;

  float acc[8][8];
#pragma unroll
  for (int i = 0; i < 8; ++i)
#pragma unroll
    for (int j = 0; j < 8; ++j) acc[i][j] = 0.f;

  for (int k0 = 0; k0 < Kdim; k0 += GBK) {
    const float4 av = *(const float4*)(Aptr + k0);
    const float4 bv = *(const float4*)(Wptr + (size_t)k0 * N);
    __syncthreads();
    As[acol + 0][arow] = av.x;
    As[acol + 1][arow] = av.y;
    As[acol + 2][arow] = av.z;
    As[acol + 3][arow] = av.w;
    *(float4*)&Bs[brow][bcol] = bv;
    __syncthreads();
#pragma unroll
    for (int k = 0; k < GBK; ++k) {
      float a[8], b[8];
      *(float4*)&a[0] = *(const float4*)&As[k][tm];
      *(float4*)&a[4] = *(const float4*)&As[k][tm + 4];
      *(float4*)&b[0] = *(const float4*)&Bs[k][tn];
      *(float4*)&b[4] = *(const float4*)&Bs[k][tn + 4];
#pragma unroll
      for (int i = 0; i < 8; ++i)
#pragma unroll
        for (int j = 0; j < 8; ++j)
          acc[i][j] = fmaf(a[i], b[j], acc[i][j]);
    }
  }

#pragma unroll
  for (int i = 0; i < 8; ++i) {
    float* crow = C + (size_t)(bm + tm + i) * N + bn + tn;
#pragma unroll
    for (int j = 0; j < 8; j += 4) {
      float4 outv;
      outv.x = acc[i][j + 0] + bias[bn + tn + j + 0];
      outv.y = acc[i][j + 1] + bias[bn + tn + j + 1];
      outv.z = acc[i][j + 2] + bias[bn + tn + j + 2];
      outv.w = acc[i][j + 3] + bias[bn + tn + j + 3];
      *(float4*)(crow + j) = outv;
    }
  }
}

// ---------------------------------------------------------------------------
// MFMA flash attention.
// Block: 256 threads = 4 waves, each wave owns 32 q-rows (block: 128 q-rows
// of one (b,h)). Swapped QK^T: scores^T[k,q] = mfma(A=K_tile, B=Q^T), so
// C cols = q (lane-local: q = lane&31, halves l/l+32 share q). Split-bf16:
// s = khi*qhi + khi*qlo + klo*qhi (residual ~2^-17). Online softmax in regs
// (pair reduce via shfl_xor 32). PV: O^T[d,q] = mfma(A=V^T, B=P^T); P^T B-
// fragment built from score regs via pack + shfl_xor 32 (C/D->B re-layout).
// K staged hi/lo in LDS stride 144B; V staged transposed stride 80B (both
// 16B-aligned, <=4-way bank aliasing on b128 reads).
// ---------------------------------------------------------------------------
#define KROW 144   // bytes per K LDS row (64 bf16 = 128B + 16 pad)
#define VROW 80    // bytes per Vt LDS row (32 bf16 = 64B + 16 pad)
#define OWST 68    // floats per epilogue row (64 + 4 pad)

__global__ __launch_bounds__(256) void flash_mfma_kernel(
    const float* __restrict__ Q, const float* __restrict__ K,
    const float* __restrict__ V, float* __restrict__ O)
{
  constexpr int S = 2048, D = 1024, H = 16;
  __shared__ __align__(16) char smem[4 * 32 * OWST * 4];  // 34816B, unions staging
  char* Khi = smem;                 // 32 rows * 144B = 4608
  char* Klo = smem + 32 * KROW;     // 4608
  char* Vt  = smem + 64 * KROW;     // 64 rows * 80B = 5120 (total 14336)
  float* Ow = (float*)smem;         // epilogue reuse

  const int qt = blockIdx.x;        // 0..15 q-tile (128 rows)
  const int bh = blockIdx.y;        // 0..31
  const int b = bh >> 4, h = bh & 15;
  const int tid = threadIdx.x;
  const int w = tid >> 6;           // wave 0..3
  const int lane = tid & 63;
  const int l31 = lane & 31;
  const int h5 = lane >> 5;         // lane half

  const size_t kvrow0 = (size_t)(b * S) * D + (size_t)h * 64;

  // ---- Q fragments, hi/lo split, 0.125 scale folded in ----
  const int qrow = qt * 128 + w * 32 + l31;
  const float* qp = Q + (size_t)(b * S + qrow) * D + h * 64;
  bf16x8 qhi[4], qlo[4];
#pragma unroll
  for (int t = 0; t < 4; ++t) {
    const float* p0 = qp + 16 * t + 8 * h5;
    float4 f0 = *(const float4*)p0;
    float4 f1 = *(const float4*)(p0 + 4);
    float fv[8] = {f0.x, f0.y, f0.z, f0.w, f1.x, f1.y, f1.z, f1.w};
    union { bf16x8 v; unsigned short s[8]; } uh, ul;
#pragma unroll
    for (int j = 0; j < 8; ++j) {
      float f = fv[j] * 0.125f;
      unsigned short hb = f2bf(f);
      uh.s[j] = hb;
      ul.s[j] = f2bf(f - bf2f(hb));
    }
    qhi[t] = uh.v;
    qlo[t] = ul.v;
  }

  f32x16 o0, o1;
#pragma unroll
  for (int r = 0; r < 16; ++r) { o0[r] = 0.f; o1[r] = 0.f; }
  float m = -1e30f, lsum = 0.f;

  // staging assignments
  const int krs = tid >> 3, c8k = (tid & 7) * 8;   // K: coalesced rows
  const int vrs = tid & 31, c8v = (tid >> 5) * 8;  // V: column-ish for LDS transpose

  for (int kb = 0; kb < S; kb += 32) {
    __syncthreads();
    {  // stage K tile as hi/lo bf16
      const float* kg = K + kvrow0 + (size_t)(kb + krs) * D + c8k;
      float4 a = *(const float4*)kg;
      float4 c = *(const float4*)(kg + 4);
      float fv[8] = {a.x, a.y, a.z, a.w, c.x, c.y, c.z, c.w};
      union { bf16x8 v; unsigned short s[8]; } uh, ul;
#pragma unroll
      for (int j = 0; j < 8; ++j) {
        unsigned short hb = f2bf(fv[j]);
        uh.s[j] = hb;
        ul.s[j] = f2bf(fv[j] - bf2f(hb));
      }
      *(bf16x8*)(Khi + krs * KROW + c8k * 2) = uh.v;
      *(bf16x8*)(Klo + krs * KROW + c8k * 2) = ul.v;
    }
    {  // stage V tile transposed (bf16)
      const float* vg = V + kvrow0 + (size_t)(kb + vrs) * D + c8v;
      float4 a = *(const float4*)vg;
      float4 c = *(const float4*)(vg + 4);
      float fv[8] = {a.x, a.y, a.z, a.w, c.x, c.y, c.z, c.w};
#pragma unroll
      for (int j = 0; j < 8; ++j)
        *(unsigned short*)(Vt + (c8v + j) * VROW + vrs * 2) = f2bf(fv[j]);
    }
    __syncthreads();

    // ---- scores^T = K · Q^T (split bf16, 12 MFMAs) ----
    f32x16 s;
#pragma unroll
    for (int r = 0; r < 16; ++r) s[r] = 0.f;
#pragma unroll
    for (int t = 0; t < 4; ++t) {
      bf16x8 ah = *(const bf16x8*)(Khi + l31 * KROW + 32 * t + 16 * h5);
      bf16x8 al = *(const bf16x8*)(Klo + l31 * KROW + 32 * t + 16 * h5);
      s = __builtin_amdgcn_mfma_f32_32x32x16_bf16(ah, qhi[t], s, 0, 0, 0);
      s = __builtin_amdgcn_mfma_f32_32x32x16_bf16(ah, qlo[t], s, 0, 0, 0);
      s = __builtin_amdgcn_mfma_f32_32x32x16_bf16(al, qhi[t], s, 0, 0, 0);
    }

    // ---- online softmax (per lane: 16 keys of its q; pair share via xor 32) ----
    float tmax = s[0];
#pragma unroll
    for (int r = 1; r < 16; ++r) tmax = fmaxf(tmax, s[r]);
    tmax = fmaxf(tmax, __shfl_xor(tmax, 32));
    const float mn = fmaxf(m, tmax);
    const float fr = __expf(m - mn);
    float ts = 0.f;
#pragma unroll
    for (int r = 0; r < 16; ++r) {
      s[r] = __expf(s[r] - mn);
      ts += s[r];
    }
    ts += __shfl_xor(ts, 32);
    lsum = lsum * fr + ts;
#pragma unroll
    for (int r = 0; r < 16; ++r) { o0[r] *= fr; o1[r] *= fr; }
    m = mn;

    // ---- P^T B-fragments + PV (O^T += V^T · P^T) ----
#pragma unroll
    for (int tp = 0; tp < 2; ++tp) {
      unsigned int wA0 = packbf(s[8 * tp + 0], s[8 * tp + 1]);
      unsigned int wA1 = packbf(s[8 * tp + 2], s[8 * tp + 3]);
      unsigned int wB0 = packbf(s[8 * tp + 4], s[8 * tp + 5]);
      unsigned int wB1 = packbf(s[8 * tp + 6], s[8 * tp + 7]);
      unsigned int snd0 = h5 ? wA0 : wB0;
      unsigned int snd1 = h5 ? wA1 : wB1;
      unsigned int rc0 = (unsigned int)__shfl_xor((int)snd0, 32);
      unsigned int rc1 = (unsigned int)__shfl_xor((int)snd1, 32);
      union { bf16x8 v; unsigned int u[4]; } pf;
      pf.u[0] = h5 ? rc0 : wA0;
      pf.u[1] = h5 ? rc1 : wA1;
      pf.u[2] = h5 ? wB0 : rc0;
      pf.u[3] = h5 ? wB1 : rc1;
      bf16x8 v0 = *(const bf16x8*)(Vt + l31 * VROW + 32 * tp + 16 * h5);
      bf16x8 v1 = *(const bf16x8*)(Vt + (32 + l31) * VROW + 32 * tp + 16 * h5);
      o0 = __builtin_amdgcn_mfma_f32_32x32x16_bf16(v0, pf.v, o0, 0, 0, 0);
      o1 = __builtin_amdgcn_mfma_f32_32x32x16_bf16(v1, pf.v, o1, 0, 0, 0);
    }
  }

  // ---- epilogue: O^T regs -> LDS transpose -> coalesced global ----
  __syncthreads();
  const float inv = 1.f / lsum;
  float* owp = Ow + w * 32 * OWST;
#pragma unroll
  for (int r = 0; r < 16; ++r) {
    const int d = (r & 3) + 8 * (r >> 2) + 4 * h5;
    owp[l31 * OWST + d]      = o0[r] * inv;
    owp[l31 * OWST + d + 32] = o1[r] * inv;
  }
  __syncthreads();
#pragma unroll
  for (int it = 0; it < 8; ++it) {
    const int row = it * 4 + (lane >> 4);
    const int col = (lane & 15) * 4;
    float4 val = *(float4*)(owp + row * OWST + col);
    const int token = b * S + qt * 128 + w * 32 + row;
    *(float4*)(O + (size_t)token * D + h * 64 + col) = val;
  }
}

// ---------------------------------------------------------------------------

extern "C" void kernel_launch(void* const* d_in, const int* in_sizes, int n_in,
                              void* d_out, int out_size, void* d_ws, size_t ws_size,
                              hipStream_t stream) {
  const float* X  = (const float*)d_in[0];
  const float* Wq = (const float*)d_in[1];
  const float* bq = (const float*)d_in[2];
  const float* Wk = (const float*)d_in[3];
  const float* bk = (const float*)d_in[4];
  const float* Wv = (const float*)d_in[5];
  const float* bv = (const float*)d_in[6];
  const float* Wo = (const float*)d_in[7];
  const float* bo = (const float*)d_in[8];
  float* out = (float*)d_out;

  const int B = 2, S = 2048, D = 1024, H = 16;
  const int M = B * S;  // 4096

  float* Qb = (float*)d_ws;
  float* Kb = Qb + (size_t)M * D;
  float* Vb = Kb + (size_t)M * D;
  float* Cc = Vb + (size_t)M * D;

  // 1. fused QKV projections
  dim3 gqkv(D / GBN, M / GBM, 3);
  gemm_bias_kernel<<<gqkv, 256, 0, stream>>>(X, Wq, Wk, Wv, bq, bk, bv,
                                             Qb, Kb, Vb, M, D, D);

  // 2. MFMA flash attention
  dim3 gattn(S / 128, B * H);
  flash_mfma_kernel<<<gattn, 256, 0, stream>>>(Qb, Kb, Vb, Cc);

  // 3. output projection
  dim3 gout(D / GBN, M / GBM, 1);
  gemm_bias_kernel<<<gout, 256, 0, stream>>>(Cc, Wo, Wo, Wo, bo, bo, bo,
                                             out, out, out, M, D, D);
}

// Round 3
// 314.930 us; speedup vs baseline: 7.8598x; 1.9395x over previous
//
#include <hip/hip_runtime.h>

// ---------------------------------------------------------------------------
// MultiHeadSelfAttention: B=2, S=2048, D=1024, H=16, hd=64, fp32 in/out.
// R3: projections moved to split-bf16 MFMA (3-product hi/lo decomposition).
//   prep: X -> Xhi/Xlo bf16; W -> W^T hi/lo bf16 (K-contiguous)
//   gemm_split_mfma: 128x128x32 tiles, global_load_lds(16B) into
//     fragment-major LDS (conflict-free linear ds_read_b128), 48 MFMA/wave/step
//   flash attention: unchanged from R2 (passed at 9.8e-4)
// ---------------------------------------------------------------------------

typedef __attribute__((ext_vector_type(8))) short bf16x8;
typedef __attribute__((ext_vector_type(16))) float f32x16;
typedef __attribute__((ext_vector_type(4))) float f32x4;
typedef __attribute__((ext_vector_type(4))) unsigned short u16x4;

__device__ __forceinline__ unsigned short f2bf(float f) {
  unsigned int u = __float_as_uint(f);
  unsigned int r = (u + 0x7FFFu + ((u >> 16) & 1u)) >> 16;  // RNE
  return (unsigned short)r;
}
__device__ __forceinline__ float bf2f(unsigned short s) {
  return __uint_as_float(((unsigned int)s) << 16);
}
__device__ __forceinline__ unsigned int packbf(float a, float b) {
  return (unsigned int)f2bf(a) | ((unsigned int)f2bf(b) << 16);
}

typedef __attribute__((address_space(1))) const void gconst_void;
typedef __attribute__((address_space(3))) void lds_void;
__device__ __forceinline__ void gload16(const void* src, void* dst) {
  __builtin_amdgcn_global_load_lds((gconst_void*)src, (lds_void*)dst, 16, 0, 0);
}

// ---------------------------------------------------------------------------
// prep 1: elementwise split fp32 -> bf16 hi + lo   (n divisible by 2048*8)
// ---------------------------------------------------------------------------
__global__ __launch_bounds__(256) void split_kernel(
    const float* __restrict__ in, unsigned short* __restrict__ hi,
    unsigned short* __restrict__ lo)
{
  const int i = (blockIdx.x * 256 + threadIdx.x) * 8;
  float4 a = *(const float4*)(in + i);
  float4 b = *(const float4*)(in + i + 4);
  float f[8] = {a.x, a.y, a.z, a.w, b.x, b.y, b.z, b.w};
  union { bf16x8 v; unsigned short s[8]; } H, L;
#pragma unroll
  for (int j = 0; j < 8; ++j) {
    unsigned short hb = f2bf(f[j]);
    H.s[j] = hb;
    L.s[j] = f2bf(f[j] - bf2f(hb));
  }
  *(bf16x8*)(hi + i) = H.v;
  *(bf16x8*)(lo + i) = L.v;
}

// ---------------------------------------------------------------------------
// prep 2: W[K][N] fp32 -> Wt[N][K] bf16 hi/lo (transpose + split), 32x32 tiles
// grid (N/32, K/32, 4) selecting one of 4 weight matrices
// ---------------------------------------------------------------------------
__global__ __launch_bounds__(256) void tsplit_kernel(
    const float* __restrict__ W0, const float* __restrict__ W1,
    const float* __restrict__ W2, const float* __restrict__ W3,
    unsigned short* __restrict__ H0, unsigned short* __restrict__ H1,
    unsigned short* __restrict__ H2, unsigned short* __restrict__ H3,
    unsigned short* __restrict__ L0, unsigned short* __restrict__ L1,
    unsigned short* __restrict__ L2, unsigned short* __restrict__ L3,
    int N, int K)
{
  const int z = blockIdx.z;
  const float* W = (z == 0) ? W0 : (z == 1) ? W1 : (z == 2) ? W2 : W3;
  unsigned short* H = (z == 0) ? H0 : (z == 1) ? H1 : (z == 2) ? H2 : H3;
  unsigned short* L = (z == 0) ? L0 : (z == 1) ? L1 : (z == 2) ? L2 : L3;

  __shared__ float t[32][33];
  const int r = threadIdx.x >> 3;         // 0..31
  const int c4 = (threadIdx.x & 7) << 2;  // 0..28
  const int n0 = blockIdx.x * 32, k0 = blockIdx.y * 32;

  float4 v = *(const float4*)(W + (size_t)(k0 + r) * N + n0 + c4);
  t[r][c4 + 0] = v.x; t[r][c4 + 1] = v.y; t[r][c4 + 2] = v.z; t[r][c4 + 3] = v.w;
  __syncthreads();

  u16x4 hv, lv;
#pragma unroll
  for (int j = 0; j < 4; ++j) {
    float f = t[c4 + j][r];  // = W[k0+c4+j][n0+r]
    unsigned short hb = f2bf(f);
    hv[j] = hb;
    lv[j] = f2bf(f - bf2f(hb));
  }
  *(u16x4*)(H + (size_t)(n0 + r) * K + k0 + c4) = hv;
  *(u16x4*)(L + (size_t)(n0 + r) * K + k0 + c4) = lv;
}

// ---------------------------------------------------------------------------
// split-bf16 MFMA GEMM: C[M][N] = A[M][K] * Bt[N][K]^T + bias
//   A given as Ahi/Alo bf16, Bt as hi/lo bf16 (both K-contiguous).
//   3 products per fragment pair: ah*bh + ah*bl + al*bh.
// 128x128 tile, 4 waves (2x2 of 64x64), BK=32, 16x16x32 MFMA.
// LDS is fragment-major: buf[frag f=row/16][lane][8 bf16] -> both the
// global_load_lds destination (linear, lane*16) and the ds_read_b128 source
// are sequential => zero bank conflicts. Per-lane global src supplies the
// scatter (row = f*16+(lane&15), col = (lane>>4)*8).
// ---------------------------------------------------------------------------
__global__ __launch_bounds__(256, 3) void gemm_split_mfma(
    const unsigned short* __restrict__ Ahi, const unsigned short* __restrict__ Alo,
    const unsigned short* __restrict__ Bh0, const unsigned short* __restrict__ Bl0,
    const unsigned short* __restrict__ Bh1, const unsigned short* __restrict__ Bl1,
    const unsigned short* __restrict__ Bh2, const unsigned short* __restrict__ Bl2,
    const float* __restrict__ bias0, const float* __restrict__ bias1,
    const float* __restrict__ bias2,
    float* __restrict__ C0, float* __restrict__ C1, float* __restrict__ C2,
    int M, int N, int K)
{
  const int z = blockIdx.z;
  const unsigned short* Bhi = (z == 0) ? Bh0 : (z == 1) ? Bh1 : Bh2;
  const unsigned short* Blo = (z == 0) ? Bl0 : (z == 1) ? Bl1 : Bl2;
  const float* bias         = (z == 0) ? bias0 : (z == 1) ? bias1 : bias2;
  float* C                  = (z == 0) ? C0 : (z == 1) ? C1 : C2;

  __shared__ __align__(16) char lds[32768];
  char* LAh = lds;
  char* LAl = lds + 8192;
  char* LBh = lds + 16384;
  char* LBl = lds + 24576;

  const int tid = threadIdx.x;
  const int wv = tid >> 6, lane = tid & 63;
  const int wr = wv >> 1, wc = wv & 1;
  const int bm = blockIdx.y * 128, bn = blockIdx.x * 128;

  // staging source: chunk c (=frag index) covers rows c*16..c*16+15
  const int sr = lane & 15;
  const int sc = (lane >> 4) * 8;
  const int c0 = wv * 2;  // this wave's two chunks: c0, c0+1
  const size_t rowA0 = (size_t)(bm + c0 * 16 + sr) * K + sc;
  const size_t rowA1 = rowA0 + (size_t)16 * K;
  const size_t rowB0 = (size_t)(bn + c0 * 16 + sr) * K + sc;
  const size_t rowB1 = rowB0 + (size_t)16 * K;
  char* dst0 = (char*)0 + c0 * 1024;        // LDS byte offsets for the 2 chunks
  char* dst1 = (char*)0 + (c0 + 1) * 1024;

  f32x4 acc[4][4];
#pragma unroll
  for (int m = 0; m < 4; ++m)
#pragma unroll
    for (int n = 0; n < 4; ++n)
#pragma unroll
      for (int j = 0; j < 4; ++j) acc[m][n][j] = 0.f;

  for (int k0 = 0; k0 < K; k0 += 32) {
    __syncthreads();  // previous compute done -> LDS reusable
    gload16(Ahi + rowA0 + k0, LAh + (size_t)(dst0 - (char*)0));
    gload16(Ahi + rowA1 + k0, LAh + (size_t)(dst1 - (char*)0));
    gload16(Alo + rowA0 + k0, LAl + (size_t)(dst0 - (char*)0));
    gload16(Alo + rowA1 + k0, LAl + (size_t)(dst1 - (char*)0));
    gload16(Bhi + rowB0 + k0, LBh + (size_t)(dst0 - (char*)0));
    gload16(Bhi + rowB1 + k0, LBh + (size_t)(dst1 - (char*)0));
    gload16(Blo + rowB0 + k0, LBl + (size_t)(dst0 - (char*)0));
    gload16(Blo + rowB1 + k0, LBl + (size_t)(dst1 - (char*)0));
    __syncthreads();  // loads visible (compiler inserts vmcnt(0) drain)

    bf16x8 ah[4], al[4];
#pragma unroll
    for (int i = 0; i < 4; ++i) {
      ah[i] = *(const bf16x8*)(LAh + (wr * 4 + i) * 1024 + lane * 16);
      al[i] = *(const bf16x8*)(LAl + (wr * 4 + i) * 1024 + lane * 16);
    }
#pragma unroll
    for (int n = 0; n < 4; ++n) {
      bf16x8 bh = *(const bf16x8*)(LBh + (wc * 4 + n) * 1024 + lane * 16);
      bf16x8 bl = *(const bf16x8*)(LBl + (wc * 4 + n) * 1024 + lane * 16);
#pragma unroll
      for (int m = 0; m < 4; ++m) {
        acc[m][n] = __builtin_amdgcn_mfma_f32_16x16x32_bf16(ah[m], bh, acc[m][n], 0, 0, 0);
        acc[m][n] = __builtin_amdgcn_mfma_f32_16x16x32_bf16(ah[m], bl, acc[m][n], 0, 0, 0);
        acc[m][n] = __builtin_amdgcn_mfma_f32_16x16x32_bf16(al[m], bh, acc[m][n], 0, 0, 0);
      }
    }
  }

  // epilogue: C/D layout col=lane&15, row=(lane>>4)*4+j
  const int cn = lane & 15, cr4 = (lane >> 4) * 4;
  float bias_v[4];
#pragma unroll
  for (int n = 0; n < 4; ++n) bias_v[n] = bias[bn + wc * 64 + n * 16 + cn];
#pragma unroll
  for (int m = 0; m < 4; ++m) {
#pragma unroll
    for (int n = 0; n < 4; ++n) {
      float* cp = C + (size_t)(bm + wr * 64 + m * 16 + cr4) * N + bn + wc * 64 + n * 16 + cn;
#pragma unroll
      for (int j = 0; j < 4; ++j) cp[(size_t)j * N] = acc[m][n][j] + bias_v[n];
    }
  }
}

// ---------------------------------------------------------------------------
// MFMA flash attention (unchanged from R2 — passed at 9.8e-4)
// ---------------------------------------------------------------------------
#define KROW 144
#define VROW 80
#define OWST 68

__global__ __launch_bounds__(256) void flash_mfma_kernel(
    const float* __restrict__ Q, const float* __restrict__ K,
    const float* __restrict__ V, float* __restrict__ O)
{
  constexpr int S = 2048, D = 1024, H = 16;
  __shared__ __align__(16) char smem[4 * 32 * OWST * 4];
  char* Khi = smem;
  char* Klo = smem + 32 * KROW;
  char* Vt  = smem + 64 * KROW;
  float* Ow = (float*)smem;

  const int qt = blockIdx.x;
  const int bh = blockIdx.y;
  const int b = bh >> 4, h = bh & 15;
  const int tid = threadIdx.x;
  const int w = tid >> 6;
  const int lane = tid & 63;
  const int l31 = lane & 31;
  const int h5 = lane >> 5;

  const size_t kvrow0 = (size_t)(b * S) * D + (size_t)h * 64;

  const int qrow = qt * 128 + w * 32 + l31;
  const float* qp = Q + (size_t)(b * S + qrow) * D + h * 64;
  bf16x8 qhi[4], qlo[4];
#pragma unroll
  for (int t = 0; t < 4; ++t) {
    const float* p0 = qp + 16 * t + 8 * h5;
    float4 f0 = *(const float4*)p0;
    float4 f1 = *(const float4*)(p0 + 4);
    float fv[8] = {f0.x, f0.y, f0.z, f0.w, f1.x, f1.y, f1.z, f1.w};
    union { bf16x8 v; unsigned short s[8]; } uh, ul;
#pragma unroll
    for (int j = 0; j < 8; ++j) {
      float f = fv[j] * 0.125f;
      unsigned short hb = f2bf(f);
      uh.s[j] = hb;
      ul.s[j] = f2bf(f - bf2f(hb));
    }
    qhi[t] = uh.v;
    qlo[t] = ul.v;
  }

  f32x16 o0, o1;
#pragma unroll
  for (int r = 0; r < 16; ++r) { o0[r] = 0.f; o1[r] = 0.f; }
  float m = -1e30f, lsum = 0.f;

  const int krs = tid >> 3, c8k = (tid & 7) * 8;
  const int vrs = tid & 31, c8v = (tid >> 5) * 8;

  for (int kb = 0; kb < S; kb += 32) {
    __syncthreads();
    {
      const float* kg = K + kvrow0 + (size_t)(kb + krs) * D + c8k;
      float4 a = *(const float4*)kg;
      float4 c = *(const float4*)(kg + 4);
      float fv[8] = {a.x, a.y, a.z, a.w, c.x, c.y, c.z, c.w};
      union { bf16x8 v; unsigned short s[8]; } uh, ul;
#pragma unroll
      for (int j = 0; j < 8; ++j) {
        unsigned short hb = f2bf(fv[j]);
        uh.s[j] = hb;
        ul.s[j] = f2bf(fv[j] - bf2f(hb));
      }
      *(bf16x8*)(Khi + krs * KROW + c8k * 2) = uh.v;
      *(bf16x8*)(Klo + krs * KROW + c8k * 2) = ul.v;
    }
    {
      const float* vg = V + kvrow0 + (size_t)(kb + vrs) * D + c8v;
      float4 a = *(const float4*)vg;
      float4 c = *(const float4*)(vg + 4);
      float fv[8] = {a.x, a.y, a.z, a.w, c.x, c.y, c.z, c.w};
#pragma unroll
      for (int j = 0; j < 8; ++j)
        *(unsigned short*)(Vt + (c8v + j) * VROW + vrs * 2) = f2bf(fv[j]);
    }
    __syncthreads();

    f32x16 s;
#pragma unroll
    for (int r = 0; r < 16; ++r) s[r] = 0.f;
#pragma unroll
    for (int t = 0; t < 4; ++t) {
      bf16x8 ah = *(const bf16x8*)(Khi + l31 * KROW + 32 * t + 16 * h5);
      bf16x8 al = *(const bf16x8*)(Klo + l31 * KROW + 32 * t + 16 * h5);
      s = __builtin_amdgcn_mfma_f32_32x32x16_bf16(ah, qhi[t], s, 0, 0, 0);
      s = __builtin_amdgcn_mfma_f32_32x32x16_bf16(ah, qlo[t], s, 0, 0, 0);
      s = __builtin_amdgcn_mfma_f32_32x32x16_bf16(al, qhi[t], s, 0, 0, 0);
    }

    float tmax = s[0];
#pragma unroll
    for (int r = 1; r < 16; ++r) tmax = fmaxf(tmax, s[r]);
    tmax = fmaxf(tmax, __shfl_xor(tmax, 32));
    const float mn = fmaxf(m, tmax);
    const float fr = __expf(m - mn);
    float ts = 0.f;
#pragma unroll
    for (int r = 0; r < 16; ++r) {
      s[r] = __expf(s[r] - mn);
      ts += s[r];
    }
    ts += __shfl_xor(ts, 32);
    lsum = lsum * fr + ts;
#pragma unroll
    for (int r = 0; r < 16; ++r) { o0[r] *= fr; o1[r] *= fr; }
    m = mn;

#pragma unroll
    for (int tp = 0; tp < 2; ++tp) {
      unsigned int wA0 = packbf(s[8 * tp + 0], s[8 * tp + 1]);
      unsigned int wA1 = packbf(s[8 * tp + 2], s[8 * tp + 3]);
      unsigned int wB0 = packbf(s[8 * tp + 4], s[8 * tp + 5]);
      unsigned int wB1 = packbf(s[8 * tp + 6], s[8 * tp + 7]);
      unsigned int snd0 = h5 ? wA0 : wB0;
      unsigned int snd1 = h5 ? wA1 : wB1;
      unsigned int rc0 = (unsigned int)__shfl_xor((int)snd0, 32);
      unsigned int rc1 = (unsigned int)__shfl_xor((int)snd1, 32);
      union { bf16x8 v; unsigned int u[4]; } pf;
      pf.u[0] = h5 ? rc0 : wA0;
      pf.u[1] = h5 ? rc1 : wA1;
      pf.u[2] = h5 ? wB0 : rc0;
      pf.u[3] = h5 ? wB1 : rc1;
      bf16x8 v0 = *(const bf16x8*)(Vt + l31 * VROW + 32 * tp + 16 * h5);
      bf16x8 v1 = *(const bf16x8*)(Vt + (32 + l31) * VROW + 32 * tp + 16 * h5);
      o0 = __builtin_amdgcn_mfma_f32_32x32x16_bf16(v0, pf.v, o0, 0, 0, 0);
      o1 = __builtin_amdgcn_mfma_f32_32x32x16_bf16(v1, pf.v, o1, 0, 0, 0);
    }
  }

  __syncthreads();
  const float inv = 1.f / lsum;
  float* owp = Ow + w * 32 * OWST;
#pragma unroll
  for (int r = 0; r < 16; ++r) {
    const int d = (r & 3) + 8 * (r >> 2) + 4 * h5;
    owp[l31 * OWST + d]      = o0[r] * inv;
    owp[l31 * OWST + d + 32] = o1[r] * inv;
  }
  __syncthreads();
#pragma unroll
  for (int it = 0; it < 8; ++it) {
    const int row = it * 4 + (lane >> 4);
    const int col = (lane & 15) * 4;
    float4 val = *(float4*)(owp + row * OWST + col);
    const int token = b * S + qt * 128 + w * 32 + row;
    *(float4*)(O + (size_t)token * D + h * 64 + col) = val;
  }
}

// ---------------------------------------------------------------------------

extern "C" void kernel_launch(void* const* d_in, const int* in_sizes, int n_in,
                              void* d_out, int out_size, void* d_ws, size_t ws_size,
                              hipStream_t stream) {
  const float* X  = (const float*)d_in[0];
  const float* Wq = (const float*)d_in[1];
  const float* bq = (const float*)d_in[2];
  const float* Wk = (const float*)d_in[3];
  const float* bk = (const float*)d_in[4];
  const float* Wv = (const float*)d_in[5];
  const float* bv = (const float*)d_in[6];
  const float* Wo = (const float*)d_in[7];
  const float* bo = (const float*)d_in[8];
  float* out = (float*)d_out;

  const int B = 2, S = 2048, D = 1024, H = 16;
  const int M = B * S;                 // 4096
  const size_t MD = (size_t)M * D;     // 4M elements

  float* Qb = (float*)d_ws;            // 16 MB each
  float* Kb = Qb + MD;
  float* Vb = Kb + MD;
  float* Cc = Vb + MD;
  unsigned short* Xhi = (unsigned short*)(Cc + MD);  // 8 MB (reused for Cc split)
  unsigned short* Xlo = Xhi + MD;                    // 8 MB
  unsigned short* Wt = Xlo + MD;                     // 8 mats x 2 MB
  unsigned short* Wth[4], *Wtl[4];
  for (int i = 0; i < 4; ++i) {
    Wth[i] = Wt + (size_t)(2 * i) * D * D;
    Wtl[i] = Wt + (size_t)(2 * i + 1) * D * D;
  }

  // prep: split X, transpose+split all 4 weight matrices
  split_kernel<<<dim3(MD / (256 * 8)), 256, 0, stream>>>(X, Xhi, Xlo);
  tsplit_kernel<<<dim3(D / 32, D / 32, 4), 256, 0, stream>>>(
      Wq, Wk, Wv, Wo, Wth[0], Wth[1], Wth[2], Wth[3],
      Wtl[0], Wtl[1], Wtl[2], Wtl[3], D, D);

  // QKV projections (split-bf16 MFMA, 3-way via grid.z)
  gemm_split_mfma<<<dim3(D / 128, M / 128, 3), 256, 0, stream>>>(
      Xhi, Xlo, Wth[0], Wtl[0], Wth[1], Wtl[1], Wth[2], Wtl[2],
      bq, bk, bv, Qb, Kb, Vb, M, D, D);

  // flash attention
  flash_mfma_kernel<<<dim3(S / 128, B * H), 256, 0, stream>>>(Qb, Kb, Vb, Cc);

  // split attention output, then output projection
  split_kernel<<<dim3(MD / (256 * 8)), 256, 0, stream>>>(Cc, Xhi, Xlo);
  gemm_split_mfma<<<dim3(D / 128, M / 128, 1), 256, 0, stream>>>(
      Xhi, Xlo, Wth[3], Wtl[3], Wth[3], Wtl[3], Wth[3], Wtl[3],
      bo, bo, bo, out, out, out, M, D, D);
}

// Round 5
// 266.862 us; speedup vs baseline: 9.2756x; 1.1801x over previous
//
#include <hip/hip_runtime.h>

// ---------------------------------------------------------------------------
// MultiHeadSelfAttention: B=2, S=2048, D=1024, H=16, hd=64, fp32 in/out.
// R5: R4 structure with the V-tile LDS staging offset bug fixed
//     ((off8 - kb)*2 -> off8*2; within-tile column is off8).
// ---------------------------------------------------------------------------

typedef __attribute__((ext_vector_type(8))) short bf16x8;
typedef __attribute__((ext_vector_type(16))) float f32x16;
typedef __attribute__((ext_vector_type(4))) float f32x4;
typedef __attribute__((ext_vector_type(4))) unsigned short u16x4;

__device__ __forceinline__ unsigned short f2bf(float f) {
  unsigned int u = __float_as_uint(f);
  unsigned int r = (u + 0x7FFFu + ((u >> 16) & 1u)) >> 16;  // RNE
  return (unsigned short)r;
}
__device__ __forceinline__ float bf2f(unsigned short s) {
  return __uint_as_float(((unsigned int)s) << 16);
}
__device__ __forceinline__ unsigned int cvtpk(float lo, float hi) {
  unsigned int r;
  asm("v_cvt_pk_bf16_f32 %0, %1, %2" : "=v"(r) : "v"(lo), "v"(hi));
  return r;
}

typedef __attribute__((address_space(1))) const void gconst_void;
typedef __attribute__((address_space(3))) void lds_void;
__device__ __forceinline__ void gload16(const void* src, void* dst) {
  __builtin_amdgcn_global_load_lds((gconst_void*)src, (lds_void*)dst, 16, 0, 0);
}

#define QSCALE 0.18033688f  // 0.125 * log2(e): softmax runs in exp2 domain

// ---------------------------------------------------------------------------
// prep: X fp32 -> bf16 hi + lo
// ---------------------------------------------------------------------------
__global__ __launch_bounds__(256) void split_kernel(
    const float* __restrict__ in, unsigned short* __restrict__ hi,
    unsigned short* __restrict__ lo)
{
  const int i = (blockIdx.x * 256 + threadIdx.x) * 8;
  float4 a = *(const float4*)(in + i);
  float4 b = *(const float4*)(in + i + 4);
  float f[8] = {a.x, a.y, a.z, a.w, b.x, b.y, b.z, b.w};
  union { bf16x8 v; unsigned short s[8]; } H, L;
#pragma unroll
  for (int j = 0; j < 8; ++j) {
    unsigned short hb = f2bf(f[j]);
    H.s[j] = hb;
    L.s[j] = f2bf(f[j] - bf2f(hb));
  }
  *(bf16x8*)(hi + i) = H.v;
  *(bf16x8*)(lo + i) = L.v;
}

// ---------------------------------------------------------------------------
// prep: W[K][N] fp32 -> Wt[N][K] bf16 hi/lo (transpose + split)
// ---------------------------------------------------------------------------
__global__ __launch_bounds__(256) void tsplit_kernel(
    const float* __restrict__ W0, const float* __restrict__ W1,
    const float* __restrict__ W2, const float* __restrict__ W3,
    unsigned short* __restrict__ H0, unsigned short* __restrict__ H1,
    unsigned short* __restrict__ H2, unsigned short* __restrict__ H3,
    unsigned short* __restrict__ L0, unsigned short* __restrict__ L1,
    unsigned short* __restrict__ L2, unsigned short* __restrict__ L3,
    int N, int K)
{
  const int z = blockIdx.z;
  const float* W = (z == 0) ? W0 : (z == 1) ? W1 : (z == 2) ? W2 : W3;
  unsigned short* H = (z == 0) ? H0 : (z == 1) ? H1 : (z == 2) ? H2 : H3;
  unsigned short* L = (z == 0) ? L0 : (z == 1) ? L1 : (z == 2) ? L2 : L3;

  __shared__ float t[32][33];
  const int r = threadIdx.x >> 3;
  const int c4 = (threadIdx.x & 7) << 2;
  const int n0 = blockIdx.x * 32, k0 = blockIdx.y * 32;

  float4 v = *(const float4*)(W + (size_t)(k0 + r) * N + n0 + c4);
  t[r][c4 + 0] = v.x; t[r][c4 + 1] = v.y; t[r][c4 + 2] = v.z; t[r][c4 + 3] = v.w;
  __syncthreads();

  u16x4 hv, lv;
#pragma unroll
  for (int j = 0; j < 4; ++j) {
    float f = t[c4 + j][r];
    unsigned short hb = f2bf(f);
    hv[j] = hb;
    lv[j] = f2bf(f - bf2f(hb));
  }
  *(u16x4*)(H + (size_t)(n0 + r) * K + k0 + c4) = hv;
  *(u16x4*)(L + (size_t)(n0 + r) * K + k0 + c4) = lv;
}

// ---------------------------------------------------------------------------
// shared split-bf16 MFMA GEMM core: 128x128 tile, 4 waves, BK=32,
// fragment-major LDS via global_load_lds(16B).
// ---------------------------------------------------------------------------
__device__ __forceinline__ void gemm_core_128(
    const unsigned short* __restrict__ Ahi, const unsigned short* __restrict__ Alo,
    const unsigned short* __restrict__ Bhi, const unsigned short* __restrict__ Blo,
    int Kdim, int bm, int bn, int wv, int lane, char* lds, f32x4 acc[4][4])
{
  char* LAh = lds;
  char* LAl = lds + 8192;
  char* LBh = lds + 16384;
  char* LBl = lds + 24576;

  const int wr = wv >> 1, wc = wv & 1;
  const int sr = lane & 15;
  const int sc = (lane >> 4) * 8;
  const int c0 = wv * 2;
  const size_t rowA0 = (size_t)(bm + c0 * 16 + sr) * Kdim + sc;
  const size_t rowA1 = rowA0 + (size_t)16 * Kdim;
  const size_t rowB0 = (size_t)(bn + c0 * 16 + sr) * Kdim + sc;
  const size_t rowB1 = rowB0 + (size_t)16 * Kdim;
  const size_t d0 = (size_t)c0 * 1024;
  const size_t d1 = (size_t)(c0 + 1) * 1024;

#pragma unroll
  for (int m = 0; m < 4; ++m)
#pragma unroll
    for (int n = 0; n < 4; ++n)
#pragma unroll
      for (int j = 0; j < 4; ++j) acc[m][n][j] = 0.f;

  for (int k0 = 0; k0 < Kdim; k0 += 32) {
    __syncthreads();
    gload16(Ahi + rowA0 + k0, LAh + d0);
    gload16(Ahi + rowA1 + k0, LAh + d1);
    gload16(Alo + rowA0 + k0, LAl + d0);
    gload16(Alo + rowA1 + k0, LAl + d1);
    gload16(Bhi + rowB0 + k0, LBh + d0);
    gload16(Bhi + rowB1 + k0, LBh + d1);
    gload16(Blo + rowB0 + k0, LBl + d0);
    gload16(Blo + rowB1 + k0, LBl + d1);
    __syncthreads();

    bf16x8 ah[4], al[4];
#pragma unroll
    for (int i = 0; i < 4; ++i) {
      ah[i] = *(const bf16x8*)(LAh + (wr * 4 + i) * 1024 + lane * 16);
      al[i] = *(const bf16x8*)(LAl + (wr * 4 + i) * 1024 + lane * 16);
    }
#pragma unroll
    for (int n = 0; n < 4; ++n) {
      bf16x8 bh = *(const bf16x8*)(LBh + (wc * 4 + n) * 1024 + lane * 16);
      bf16x8 bl = *(const bf16x8*)(LBl + (wc * 4 + n) * 1024 + lane * 16);
#pragma unroll
      for (int m = 0; m < 4; ++m) {
        acc[m][n] = __builtin_amdgcn_mfma_f32_16x16x32_bf16(ah[m], bh, acc[m][n], 0, 0, 0);
        acc[m][n] = __builtin_amdgcn_mfma_f32_16x16x32_bf16(ah[m], bl, acc[m][n], 0, 0, 0);
        acc[m][n] = __builtin_amdgcn_mfma_f32_16x16x32_bf16(al[m], bh, acc[m][n], 0, 0, 0);
      }
    }
  }
}

// ---------------------------------------------------------------------------
// QKV GEMM with fused bf16 epilogues:
//   z=0: Qhi/Qlo bf16 row-major, scaled by QSCALE (softmax exp2 domain)
//   z=1: Khi/Klo bf16 row-major
//   z=2: V^T bf16 [b*16+h][64][2048]  (u16x4 packs along tokens)
// ---------------------------------------------------------------------------
__global__ __launch_bounds__(256, 3) void gemm_qkv_mfma(
    const unsigned short* __restrict__ Ahi, const unsigned short* __restrict__ Alo,
    const unsigned short* __restrict__ Bh0, const unsigned short* __restrict__ Bl0,
    const unsigned short* __restrict__ Bh1, const unsigned short* __restrict__ Bl1,
    const unsigned short* __restrict__ Bh2, const unsigned short* __restrict__ Bl2,
    const float* __restrict__ bias0, const float* __restrict__ bias1,
    const float* __restrict__ bias2,
    unsigned short* __restrict__ Qhi, unsigned short* __restrict__ Qlo,
    unsigned short* __restrict__ Khi, unsigned short* __restrict__ Klo,
    unsigned short* __restrict__ Vtg,
    int M, int N, int Kdim)
{
  const int z = blockIdx.z;
  const unsigned short* Bhi = (z == 0) ? Bh0 : (z == 1) ? Bh1 : Bh2;
  const unsigned short* Blo = (z == 0) ? Bl0 : (z == 1) ? Bl1 : Bl2;
  const float* bias         = (z == 0) ? bias0 : (z == 1) ? bias1 : bias2;

  __shared__ __align__(16) char lds[32768];
  const int tid = threadIdx.x;
  const int wv = tid >> 6, lane = tid & 63;
  const int wr = wv >> 1, wc = wv & 1;
  const int bm = blockIdx.y * 128, bn = blockIdx.x * 128;

  f32x4 acc[4][4];
  gemm_core_128(Ahi, Alo, Bhi, Blo, Kdim, bm, bn, wv, lane, lds, acc);

  const int cn = lane & 15, cr4 = (lane >> 4) * 4;
  float bias_v[4];
#pragma unroll
  for (int n = 0; n < 4; ++n) bias_v[n] = bias[bn + wc * 64 + n * 16 + cn];

  if (z == 2) {
    // V^T store: 4 consecutive tokens -> one u16x4
#pragma unroll
    for (int m = 0; m < 4; ++m) {
      const int r0 = bm + wr * 64 + m * 16 + cr4;
      const int bb = r0 >> 11, ss = r0 & 2047;
#pragma unroll
      for (int n = 0; n < 4; ++n) {
        const int col = bn + wc * 64 + n * 16 + cn;
        const int h = col >> 6, dh = col & 63;
        u16x4 pv;
#pragma unroll
        for (int j = 0; j < 4; ++j) pv[j] = f2bf(acc[m][n][j] + bias_v[n]);
        *(u16x4*)(Vtg + ((size_t)((bb << 4) + h) * 64 + dh) * 2048 + ss) = pv;
      }
    }
  } else {
    const float qs = (z == 0) ? QSCALE : 1.0f;
    unsigned short* Hd = (z == 0) ? Qhi : Khi;
    unsigned short* Ld = (z == 0) ? Qlo : Klo;
#pragma unroll
    for (int m = 0; m < 4; ++m) {
#pragma unroll
      for (int n = 0; n < 4; ++n) {
        const size_t base = (size_t)(bm + wr * 64 + m * 16 + cr4) * N + bn + wc * 64 + n * 16 + cn;
#pragma unroll
        for (int j = 0; j < 4; ++j) {
          float v = (acc[m][n][j] + bias_v[n]) * qs;
          unsigned short hb = f2bf(v);
          Hd[base + (size_t)j * N] = hb;
          Ld[base + (size_t)j * N] = f2bf(v - bf2f(hb));
        }
      }
    }
  }
}

// ---------------------------------------------------------------------------
// output projection: fp32 epilogue + bias
// ---------------------------------------------------------------------------
__global__ __launch_bounds__(256, 3) void gemm_out_mfma(
    const unsigned short* __restrict__ Ahi, const unsigned short* __restrict__ Alo,
    const unsigned short* __restrict__ Bhi, const unsigned short* __restrict__ Blo,
    const float* __restrict__ bias, float* __restrict__ C,
    int M, int N, int Kdim)
{
  __shared__ __align__(16) char lds[32768];
  const int tid = threadIdx.x;
  const int wv = tid >> 6, lane = tid & 63;
  const int wr = wv >> 1, wc = wv & 1;
  const int bm = blockIdx.y * 128, bn = blockIdx.x * 128;

  f32x4 acc[4][4];
  gemm_core_128(Ahi, Alo, Bhi, Blo, Kdim, bm, bn, wv, lane, lds, acc);

  const int cn = lane & 15, cr4 = (lane >> 4) * 4;
  float bias_v[4];
#pragma unroll
  for (int n = 0; n < 4; ++n) bias_v[n] = bias[bn + wc * 64 + n * 16 + cn];
#pragma unroll
  for (int m = 0; m < 4; ++m) {
#pragma unroll
    for (int n = 0; n < 4; ++n) {
      float* cp = C + (size_t)(bm + wr * 64 + m * 16 + cr4) * N + bn + wc * 64 + n * 16 + cn;
#pragma unroll
      for (int j = 0; j < 4; ++j) cp[(size_t)j * N] = acc[m][n][j] + bias_v[n];
    }
  }
}

// ---------------------------------------------------------------------------
// MFMA flash attention, all-bf16 inputs. KVBLK=64, exp2-domain softmax,
// defer-max (THR=8 in log2), cvt_pk P-packing. Epilogue writes Cc hi/lo bf16.
// ---------------------------------------------------------------------------
#define KROW 144   // 64 bf16 + 8 pad = 144B rows (4-way max bank aliasing)
#define OWST 68

__global__ __launch_bounds__(256) void flash_mfma_kernel(
    const unsigned short* __restrict__ Qhi, const unsigned short* __restrict__ Qlo,
    const unsigned short* __restrict__ Khi, const unsigned short* __restrict__ Klo,
    const unsigned short* __restrict__ Vtg,
    unsigned short* __restrict__ Cchi, unsigned short* __restrict__ Cclo)
{
  constexpr int S = 2048, D = 1024;
  __shared__ __align__(16) char smem[34816];
  char* KhiL = smem;                // 64*144 = 9216
  char* KloL = smem + 9216;
  char* VtL  = smem + 18432;        // 64*144 = 9216 (27648 total)
  float* Ow  = (float*)smem;        // epilogue reuse

  // XCD swizzle: 64 consecutive blocks (4 heads) per XCD
  const int lin = blockIdx.y * 16 + blockIdx.x;
  const int swz = (lin & 7) * 64 + (lin >> 3);
  const int qt = swz & 15;
  const int bh = swz >> 4;
  const int b = bh >> 4, h = bh & 15;

  const int tid = threadIdx.x;
  const int w = tid >> 6, lane = tid & 63;
  const int l31 = lane & 31, h5 = lane >> 5;

  // ---- Q fragments (pre-scaled, pre-split) ----
  const int qrow = qt * 128 + w * 32 + l31;
  const size_t qbase = (size_t)(b * S + qrow) * D + h * 64;
  bf16x8 qhi[4], qlo[4];
#pragma unroll
  for (int t = 0; t < 4; ++t) {
    qhi[t] = *(const bf16x8*)(Qhi + qbase + 16 * t + 8 * h5);
    qlo[t] = *(const bf16x8*)(Qlo + qbase + 16 * t + 8 * h5);
  }

  f32x16 o0, o1;
#pragma unroll
  for (int r = 0; r < 16; ++r) { o0[r] = 0.f; o1[r] = 0.f; }
  float m = -1e30f, lsum = 0.f;

  // staging indices: 2 keys (and 2 d-rows) per thread, 16B chunks
  const int keyA = tid >> 3;
  const int off8 = (tid & 7) * 8;          // ushort offset (16B)
  const unsigned short* KhiG = Khi + (size_t)(b * S) * D + h * 64;
  const unsigned short* KloG = Klo + (size_t)(b * S) * D + h * 64;
  const unsigned short* VtGb = Vtg + (size_t)bh * 64 * 2048;

  const auto pv_step = [&](const f32x16& s, const int koff) {
#pragma unroll
    for (int tp = 0; tp < 2; ++tp) {
      unsigned int wA0 = cvtpk(s[8 * tp + 0], s[8 * tp + 1]);
      unsigned int wA1 = cvtpk(s[8 * tp + 2], s[8 * tp + 3]);
      unsigned int wB0 = cvtpk(s[8 * tp + 4], s[8 * tp + 5]);
      unsigned int wB1 = cvtpk(s[8 * tp + 6], s[8 * tp + 7]);
      unsigned int snd0 = h5 ? wA0 : wB0;
      unsigned int snd1 = h5 ? wA1 : wB1;
      unsigned int rc0 = (unsigned int)__shfl_xor((int)snd0, 32);
      unsigned int rc1 = (unsigned int)__shfl_xor((int)snd1, 32);
      union { bf16x8 v; unsigned int u[4]; } pf;
      pf.u[0] = h5 ? rc0 : wA0;
      pf.u[1] = h5 ? rc1 : wA1;
      pf.u[2] = h5 ? wB0 : rc0;
      pf.u[3] = h5 ? wB1 : rc1;
      bf16x8 v0 = *(const bf16x8*)(VtL + l31 * KROW + koff + 32 * tp + 16 * h5);
      bf16x8 v1 = *(const bf16x8*)(VtL + (32 + l31) * KROW + koff + 32 * tp + 16 * h5);
      o0 = __builtin_amdgcn_mfma_f32_32x32x16_bf16(v0, pf.v, o0, 0, 0, 0);
      o1 = __builtin_amdgcn_mfma_f32_32x32x16_bf16(v1, pf.v, o1, 0, 0, 0);
    }
  };

  for (int kb = 0; kb < S; kb += 64) {
    // issue global loads early (hide under previous tile's compute)
    const size_t kro = (size_t)(kb + keyA) * D + off8;
    bf16x8 rKh0 = *(const bf16x8*)(KhiG + kro);
    bf16x8 rKh1 = *(const bf16x8*)(KhiG + kro + (size_t)32 * D);
    bf16x8 rKl0 = *(const bf16x8*)(KloG + kro);
    bf16x8 rKl1 = *(const bf16x8*)(KloG + kro + (size_t)32 * D);
    const size_t vro = (size_t)keyA * 2048 + kb + off8;
    bf16x8 rV0 = *(const bf16x8*)(VtGb + vro);
    bf16x8 rV1 = *(const bf16x8*)(VtGb + vro + (size_t)32 * 2048);

    __syncthreads();  // previous tile's LDS reads done
    *(bf16x8*)(KhiL + keyA * KROW + off8 * 2)        = rKh0;
    *(bf16x8*)(KhiL + (keyA + 32) * KROW + off8 * 2) = rKh1;
    *(bf16x8*)(KloL + keyA * KROW + off8 * 2)        = rKl0;
    *(bf16x8*)(KloL + (keyA + 32) * KROW + off8 * 2) = rKl1;
    *(bf16x8*)(VtL + keyA * KROW + off8 * 2)         = rV0;  // row=d (keyA), col=off8 within tile
    *(bf16x8*)(VtL + (keyA + 32) * KROW + off8 * 2)  = rV1;
    __syncthreads();

    // ---- scores^T (exp2 domain; scale folded into Q) ----
    f32x16 s0, s1;
#pragma unroll
    for (int r = 0; r < 16; ++r) { s0[r] = 0.f; s1[r] = 0.f; }
#pragma unroll
    for (int t = 0; t < 4; ++t) {
      bf16x8 a0h = *(const bf16x8*)(KhiL + l31 * KROW + 32 * t + 16 * h5);
      bf16x8 a0l = *(const bf16x8*)(KloL + l31 * KROW + 32 * t + 16 * h5);
      bf16x8 a1h = *(const bf16x8*)(KhiL + (32 + l31) * KROW + 32 * t + 16 * h5);
      bf16x8 a1l = *(const bf16x8*)(KloL + (32 + l31) * KROW + 32 * t + 16 * h5);
      s0 = __builtin_amdgcn_mfma_f32_32x32x16_bf16(a0h, qhi[t], s0, 0, 0, 0);
      s0 = __builtin_amdgcn_mfma_f32_32x32x16_bf16(a0h, qlo[t], s0, 0, 0, 0);
      s0 = __builtin_amdgcn_mfma_f32_32x32x16_bf16(a0l, qhi[t], s0, 0, 0, 0);
      s1 = __builtin_amdgcn_mfma_f32_32x32x16_bf16(a1h, qhi[t], s1, 0, 0, 0);
      s1 = __builtin_amdgcn_mfma_f32_32x32x16_bf16(a1h, qlo[t], s1, 0, 0, 0);
      s1 = __builtin_amdgcn_mfma_f32_32x32x16_bf16(a1l, qhi[t], s1, 0, 0, 0);
    }

    // ---- online softmax (exp2 domain) with defer-max ----
    float tmax = s0[0];
#pragma unroll
    for (int r = 1; r < 16; ++r) tmax = fmaxf(tmax, s0[r]);
#pragma unroll
    for (int r = 0; r < 16; ++r) tmax = fmaxf(tmax, s1[r]);
    tmax = fmaxf(tmax, __shfl_xor(tmax, 32));
    if (!__all(tmax - m <= 8.0f)) {
      const float mn = fmaxf(m, tmax);
      const float fr = exp2f(m - mn);
      lsum *= fr;
#pragma unroll
      for (int r = 0; r < 16; ++r) { o0[r] *= fr; o1[r] *= fr; }
      m = mn;
    }
    float ts = 0.f;
#pragma unroll
    for (int r = 0; r < 16; ++r) { s0[r] = exp2f(s0[r] - m); ts += s0[r]; }
#pragma unroll
    for (int r = 0; r < 16; ++r) { s1[r] = exp2f(s1[r] - m); ts += s1[r]; }
    ts += __shfl_xor(ts, 32);
    lsum += ts;

    pv_step(s0, 0);
    pv_step(s1, 64);
  }

  // ---- epilogue: O^T -> LDS transpose -> split bf16 hi/lo stores ----
  __syncthreads();
  const float inv = 1.f / lsum;
  float* owp = Ow + w * 32 * OWST;
#pragma unroll
  for (int r = 0; r < 16; ++r) {
    const int d = (r & 3) + 8 * (r >> 2) + 4 * h5;
    owp[l31 * OWST + d]      = o0[r] * inv;
    owp[l31 * OWST + d + 32] = o1[r] * inv;
  }
  __syncthreads();
#pragma unroll
  for (int it = 0; it < 8; ++it) {
    const int row = it * 4 + (lane >> 4);
    const int col = (lane & 15) * 4;
    float4 val = *(float4*)(owp + row * OWST + col);
    const int token = b * S + qt * 128 + w * 32 + row;
    const size_t base = (size_t)token * D + h * 64 + col;
    u16x4 hv, lv;
    float fv[4] = {val.x, val.y, val.z, val.w};
#pragma unroll
    for (int j = 0; j < 4; ++j) {
      unsigned short hb = f2bf(fv[j]);
      hv[j] = hb;
      lv[j] = f2bf(fv[j] - bf2f(hb));
    }
    *(u16x4*)(Cchi + base) = hv;
    *(u16x4*)(Cclo + base) = lv;
  }
}

// ---------------------------------------------------------------------------

extern "C" void kernel_launch(void* const* d_in, const int* in_sizes, int n_in,
                              void* d_out, int out_size, void* d_ws, size_t ws_size,
                              hipStream_t stream) {
  const float* X  = (const float*)d_in[0];
  const float* Wq = (const float*)d_in[1];
  const float* bq = (const float*)d_in[2];
  const float* Wk = (const float*)d_in[3];
  const float* bk = (const float*)d_in[4];
  const float* Wv = (const float*)d_in[5];
  const float* bv = (const float*)d_in[6];
  const float* Wo = (const float*)d_in[7];
  const float* bo = (const float*)d_in[8];
  float* out = (float*)d_out;

  const int B = 2, S = 2048, D = 1024;
  const int M = B * S;                 // 4096
  const size_t MD = (size_t)M * D;     // 4M elements

  unsigned short* Xhi  = (unsigned short*)d_ws;  // each buffer: MD ushorts = 8MB
  unsigned short* Xlo  = Xhi + MD;
  unsigned short* Qhi  = Xlo + MD;
  unsigned short* Qlo  = Qhi + MD;
  unsigned short* Khi  = Qlo + MD;
  unsigned short* Klo  = Khi + MD;
  unsigned short* Vtg  = Klo + MD;
  unsigned short* Cchi = Vtg + MD;
  unsigned short* Cclo = Cchi + MD;
  unsigned short* Wt   = Cclo + MD;    // 8 x D*D ushorts = 16MB
  unsigned short *Wth[4], *Wtl[4];
  for (int i = 0; i < 4; ++i) {
    Wth[i] = Wt + (size_t)(2 * i) * D * D;
    Wtl[i] = Wt + (size_t)(2 * i + 1) * D * D;
  }

  split_kernel<<<dim3(MD / (256 * 8)), 256, 0, stream>>>(X, Xhi, Xlo);
  tsplit_kernel<<<dim3(D / 32, D / 32, 4), 256, 0, stream>>>(
      Wq, Wk, Wv, Wo, Wth[0], Wth[1], Wth[2], Wth[3],
      Wtl[0], Wtl[1], Wtl[2], Wtl[3], D, D);

  gemm_qkv_mfma<<<dim3(D / 128, M / 128, 3), 256, 0, stream>>>(
      Xhi, Xlo, Wth[0], Wtl[0], Wth[1], Wtl[1], Wth[2], Wtl[2],
      bq, bk, bv, Qhi, Qlo, Khi, Klo, Vtg, M, D, D);

  flash_mfma_kernel<<<dim3(16, 32), 256, 0, stream>>>(
      Qhi, Qlo, Khi, Klo, Vtg, Cchi, Cclo);

  gemm_out_mfma<<<dim3(D / 128, M / 128, 1), 256, 0, stream>>>(
      Cchi, Cclo, Wth[3], Wtl[3], bo, out, M, D, D);
}

// Round 6
// 167.598 us; speedup vs baseline: 14.7692x; 1.5923x over previous
//
#include <hip/hip_runtime.h>

// ---------------------------------------------------------------------------
// MultiHeadSelfAttention: B=2, S=2048, D=1024, H=16, hd=64, fp32 in/out.
// R6: full pipeline in single-product f16 MFMA (11 mantissa bits suffice for
//     the 5.2e-3 absmax budget; error model in journal). Deletes the hi/lo
//     split paths everywhere: GEMM 3->1 product, QK^T 3->1 product.
//     Structure/layout/shuffles identical to passing R5.
// ---------------------------------------------------------------------------

typedef _Float16 f16;
typedef __attribute__((ext_vector_type(8))) _Float16 f16x8;
typedef __attribute__((ext_vector_type(4))) _Float16 f16x4;
typedef __attribute__((ext_vector_type(16))) float f32x16;
typedef __attribute__((ext_vector_type(4))) float f32x4;

__device__ __forceinline__ unsigned int pkf16(float a, float b) {
  union { _Float16 h[2]; unsigned int u; } r;
  r.h[0] = (_Float16)a;  // low 16 bits = element 0 (matches bf16 packbf order)
  r.h[1] = (_Float16)b;
  return r.u;
}

typedef __attribute__((address_space(1))) const void gconst_void;
typedef __attribute__((address_space(3))) void lds_void;
__device__ __forceinline__ void gload16(const void* src, void* dst) {
  __builtin_amdgcn_global_load_lds((gconst_void*)src, (lds_void*)dst, 16, 0, 0);
}

#define QSCALE 0.18033688f  // 0.125 * log2(e): softmax runs in exp2 domain

// ---------------------------------------------------------------------------
// prep: X fp32 -> f16
// ---------------------------------------------------------------------------
__global__ __launch_bounds__(256) void to_f16_kernel(
    const float* __restrict__ in, f16* __restrict__ out)
{
  const int i = (blockIdx.x * 256 + threadIdx.x) * 8;
  float4 a = *(const float4*)(in + i);
  float4 b = *(const float4*)(in + i + 4);
  f16x8 o;
  o[0] = (f16)a.x; o[1] = (f16)a.y; o[2] = (f16)a.z; o[3] = (f16)a.w;
  o[4] = (f16)b.x; o[5] = (f16)b.y; o[6] = (f16)b.z; o[7] = (f16)b.w;
  *(f16x8*)(out + i) = o;
}

// ---------------------------------------------------------------------------
// prep: W[K][N] fp32 -> Wt[N][K] f16 (transpose + convert), 32x32 tiles
// ---------------------------------------------------------------------------
__global__ __launch_bounds__(256) void tconv_kernel(
    const float* __restrict__ W0, const float* __restrict__ W1,
    const float* __restrict__ W2, const float* __restrict__ W3,
    f16* __restrict__ T0, f16* __restrict__ T1,
    f16* __restrict__ T2, f16* __restrict__ T3,
    int N, int K)
{
  const int z = blockIdx.z;
  const float* W = (z == 0) ? W0 : (z == 1) ? W1 : (z == 2) ? W2 : W3;
  f16* T = (z == 0) ? T0 : (z == 1) ? T1 : (z == 2) ? T2 : T3;

  __shared__ float t[32][33];
  const int r = threadIdx.x >> 3;
  const int c4 = (threadIdx.x & 7) << 2;
  const int n0 = blockIdx.x * 32, k0 = blockIdx.y * 32;

  float4 v = *(const float4*)(W + (size_t)(k0 + r) * N + n0 + c4);
  t[r][c4 + 0] = v.x; t[r][c4 + 1] = v.y; t[r][c4 + 2] = v.z; t[r][c4 + 3] = v.w;
  __syncthreads();

  f16x4 hv;
#pragma unroll
  for (int j = 0; j < 4; ++j) hv[j] = (f16)t[c4 + j][r];
  *(f16x4*)(T + (size_t)(n0 + r) * K + k0 + c4) = hv;
}

// ---------------------------------------------------------------------------
// f16 MFMA GEMM core: C[M][N] = A[M][K] * Bt[N][K]^T
// 128x128 tile, 4 waves (2x2 of 64x64), BK=32, 16x16x32 MFMA, single product.
// Fragment-major LDS (frag f = rows f*16..f*16+15; lane: row=l&15,
// kofs=(l>>4)*8) -> global_load_lds dest and ds_read_b128 both linear.
// ---------------------------------------------------------------------------
__device__ __forceinline__ void gemm_core_f16(
    const f16* __restrict__ A, const f16* __restrict__ Bt,
    int Kdim, int bm, int bn, int wv, int lane, char* lds, f32x4 acc[4][4])
{
  char* LA = lds;          // 8192B
  char* LB = lds + 8192;   // 8192B

  const int wr = wv >> 1, wc = wv & 1;
  const int sr = lane & 15;
  const int sc = (lane >> 4) * 8;
  const int c0 = wv * 2;
  const size_t rowA0 = (size_t)(bm + c0 * 16 + sr) * Kdim + sc;
  const size_t rowA1 = rowA0 + (size_t)16 * Kdim;
  const size_t rowB0 = (size_t)(bn + c0 * 16 + sr) * Kdim + sc;
  const size_t rowB1 = rowB0 + (size_t)16 * Kdim;
  const size_t d0 = (size_t)c0 * 1024;
  const size_t d1 = (size_t)(c0 + 1) * 1024;

#pragma unroll
  for (int m = 0; m < 4; ++m)
#pragma unroll
    for (int n = 0; n < 4; ++n)
#pragma unroll
      for (int j = 0; j < 4; ++j) acc[m][n][j] = 0.f;

  for (int k0 = 0; k0 < Kdim; k0 += 32) {
    __syncthreads();
    gload16(A + rowA0 + k0, LA + d0);
    gload16(A + rowA1 + k0, LA + d1);
    gload16(Bt + rowB0 + k0, LB + d0);
    gload16(Bt + rowB1 + k0, LB + d1);
    __syncthreads();

    f16x8 a[4];
#pragma unroll
    for (int i = 0; i < 4; ++i)
      a[i] = *(const f16x8*)(LA + (wr * 4 + i) * 1024 + lane * 16);
#pragma unroll
    for (int n = 0; n < 4; ++n) {
      f16x8 b = *(const f16x8*)(LB + (wc * 4 + n) * 1024 + lane * 16);
#pragma unroll
      for (int m = 0; m < 4; ++m)
        acc[m][n] = __builtin_amdgcn_mfma_f32_16x16x32_f16(a[m], b, acc[m][n], 0, 0, 0);
    }
  }
}

// ---------------------------------------------------------------------------
// QKV GEMM, f16 epilogues:
//   z=0: Q f16 row-major scaled by QSCALE; z=1: K f16 row-major;
//   z=2: V^T f16 [b*16+h][64][2048]
// ---------------------------------------------------------------------------
__global__ __launch_bounds__(256, 3) void gemm_qkv_f16(
    const f16* __restrict__ A,
    const f16* __restrict__ B0, const f16* __restrict__ B1, const f16* __restrict__ B2,
    const float* __restrict__ bias0, const float* __restrict__ bias1,
    const float* __restrict__ bias2,
    f16* __restrict__ Qh, f16* __restrict__ Kh, f16* __restrict__ Vtg,
    int M, int N, int Kdim)
{
  const int z = blockIdx.z;
  const f16* Bt = (z == 0) ? B0 : (z == 1) ? B1 : B2;
  const float* bias = (z == 0) ? bias0 : (z == 1) ? bias1 : bias2;

  __shared__ __align__(16) char lds[16384];
  const int tid = threadIdx.x;
  const int wv = tid >> 6, lane = tid & 63;
  const int wr = wv >> 1, wc = wv & 1;
  const int bm = blockIdx.y * 128, bn = blockIdx.x * 128;

  f32x4 acc[4][4];
  gemm_core_f16(A, Bt, Kdim, bm, bn, wv, lane, lds, acc);

  const int cn = lane & 15, cr4 = (lane >> 4) * 4;
  float bias_v[4];
#pragma unroll
  for (int n = 0; n < 4; ++n) bias_v[n] = bias[bn + wc * 64 + n * 16 + cn];

  if (z == 2) {
    // V^T store: 4 consecutive tokens -> one f16x4
#pragma unroll
    for (int m = 0; m < 4; ++m) {
      const int r0 = bm + wr * 64 + m * 16 + cr4;
      const int bb = r0 >> 11, ss = r0 & 2047;
#pragma unroll
      for (int n = 0; n < 4; ++n) {
        const int col = bn + wc * 64 + n * 16 + cn;
        const int h = col >> 6, dh = col & 63;
        f16x4 pv;
#pragma unroll
        for (int j = 0; j < 4; ++j) pv[j] = (f16)(acc[m][n][j] + bias_v[n]);
        *(f16x4*)(Vtg + ((size_t)((bb << 4) + h) * 64 + dh) * 2048 + ss) = pv;
      }
    }
  } else {
    const float qs = (z == 0) ? QSCALE : 1.0f;
    f16* Dst = (z == 0) ? Qh : Kh;
#pragma unroll
    for (int m = 0; m < 4; ++m) {
#pragma unroll
      for (int n = 0; n < 4; ++n) {
        const size_t base = (size_t)(bm + wr * 64 + m * 16 + cr4) * N + bn + wc * 64 + n * 16 + cn;
#pragma unroll
        for (int j = 0; j < 4; ++j)
          Dst[base + (size_t)j * N] = (f16)((acc[m][n][j] + bias_v[n]) * qs);
      }
    }
  }
}

// ---------------------------------------------------------------------------
// output projection: fp32 epilogue + bias
// ---------------------------------------------------------------------------
__global__ __launch_bounds__(256, 3) void gemm_out_f16(
    const f16* __restrict__ A, const f16* __restrict__ Bt,
    const float* __restrict__ bias, float* __restrict__ C,
    int M, int N, int Kdim)
{
  __shared__ __align__(16) char lds[16384];
  const int tid = threadIdx.x;
  const int wv = tid >> 6, lane = tid & 63;
  const int wr = wv >> 1, wc = wv & 1;
  const int bm = blockIdx.y * 128, bn = blockIdx.x * 128;

  f32x4 acc[4][4];
  gemm_core_f16(A, Bt, Kdim, bm, bn, wv, lane, lds, acc);

  const int cn = lane & 15, cr4 = (lane >> 4) * 4;
  float bias_v[4];
#pragma unroll
  for (int n = 0; n < 4; ++n) bias_v[n] = bias[bn + wc * 64 + n * 16 + cn];
#pragma unroll
  for (int m = 0; m < 4; ++m) {
#pragma unroll
    for (int n = 0; n < 4; ++n) {
      float* cp = C + (size_t)(bm + wr * 64 + m * 16 + cr4) * N + bn + wc * 64 + n * 16 + cn;
#pragma unroll
      for (int j = 0; j < 4; ++j) cp[(size_t)j * N] = acc[m][n][j] + bias_v[n];
    }
  }
}

// ---------------------------------------------------------------------------
// MFMA flash attention, f16. KVBLK=64, exp2-domain softmax, defer-max.
// Swapped QK^T (A=K tile, B=Q^T), PV via O^T = V^T . P^T with the R2-verified
// pack+shfl_xor(32) C/D->B relayout. Single-product f16 QK^T.
// ---------------------------------------------------------------------------
#define KROW 144   // 64 f16 = 128B + 16 pad
#define OWST 68

__global__ __launch_bounds__(256) void flash_f16_kernel(
    const f16* __restrict__ Qh, const f16* __restrict__ Kh,
    const f16* __restrict__ Vtg, f16* __restrict__ Cc)
{
  constexpr int S = 2048, D = 1024;
  __shared__ __align__(16) char smem[34816];
  char* KL  = smem;                 // 64*144 = 9216
  char* VtL = smem + 9216;          // 9216 (18432 total)
  float* Ow = (float*)smem;         // epilogue reuse

  // XCD swizzle: 64 consecutive blocks (4 heads) per XCD
  const int lin = blockIdx.y * 16 + blockIdx.x;
  const int swz = (lin & 7) * 64 + (lin >> 3);
  const int qt = swz & 15;
  const int bh = swz >> 4;
  const int b = bh >> 4, h = bh & 15;

  const int tid = threadIdx.x;
  const int w = tid >> 6, lane = tid & 63;
  const int l31 = lane & 31, h5 = lane >> 5;

  // ---- Q fragments (pre-scaled f16) ----
  const int qrow = qt * 128 + w * 32 + l31;
  const size_t qbase = (size_t)(b * S + qrow) * D + h * 64;
  f16x8 qf[4];
#pragma unroll
  for (int t = 0; t < 4; ++t)
    qf[t] = *(const f16x8*)(Qh + qbase + 16 * t + 8 * h5);

  f32x16 o0, o1;
#pragma unroll
  for (int r = 0; r < 16; ++r) { o0[r] = 0.f; o1[r] = 0.f; }
  float m = -1e30f, lsum = 0.f;

  // staging: 2 keys (and 2 d-rows) per thread, 16B chunks
  const int keyA = tid >> 3;
  const int off8 = (tid & 7) * 8;
  const f16* KG = Kh + (size_t)(b * S) * D + h * 64;
  const f16* VG = Vtg + (size_t)bh * 64 * 2048;

  const auto pv_step = [&](const f32x16& s, const int koff) {
#pragma unroll
    for (int tp = 0; tp < 2; ++tp) {
      unsigned int wA0 = pkf16(s[8 * tp + 0], s[8 * tp + 1]);
      unsigned int wA1 = pkf16(s[8 * tp + 2], s[8 * tp + 3]);
      unsigned int wB0 = pkf16(s[8 * tp + 4], s[8 * tp + 5]);
      unsigned int wB1 = pkf16(s[8 * tp + 6], s[8 * tp + 7]);
      unsigned int snd0 = h5 ? wA0 : wB0;
      unsigned int snd1 = h5 ? wA1 : wB1;
      unsigned int rc0 = (unsigned int)__shfl_xor((int)snd0, 32);
      unsigned int rc1 = (unsigned int)__shfl_xor((int)snd1, 32);
      union { f16x8 v; unsigned int u[4]; } pf;
      pf.u[0] = h5 ? rc0 : wA0;
      pf.u[1] = h5 ? rc1 : wA1;
      pf.u[2] = h5 ? wB0 : rc0;
      pf.u[3] = h5 ? wB1 : rc1;
      f16x8 v0 = *(const f16x8*)(VtL + l31 * KROW + koff + 32 * tp + 16 * h5);
      f16x8 v1 = *(const f16x8*)(VtL + (32 + l31) * KROW + koff + 32 * tp + 16 * h5);
      o0 = __builtin_amdgcn_mfma_f32_32x32x16_f16(v0, pf.v, o0, 0, 0, 0);
      o1 = __builtin_amdgcn_mfma_f32_32x32x16_f16(v1, pf.v, o1, 0, 0, 0);
    }
  };

  for (int kb = 0; kb < S; kb += 64) {
    // reg-stage next tile (issued before the barrier; hides under drain)
    const size_t kro = (size_t)(kb + keyA) * D + off8;
    f16x8 rK0 = *(const f16x8*)(KG + kro);
    f16x8 rK1 = *(const f16x8*)(KG + kro + (size_t)32 * D);
    const size_t vro = (size_t)keyA * 2048 + kb + off8;
    f16x8 rV0 = *(const f16x8*)(VG + vro);
    f16x8 rV1 = *(const f16x8*)(VG + vro + (size_t)32 * 2048);

    __syncthreads();
    *(f16x8*)(KL + keyA * KROW + off8 * 2)         = rK0;
    *(f16x8*)(KL + (keyA + 32) * KROW + off8 * 2)  = rK1;
    *(f16x8*)(VtL + keyA * KROW + off8 * 2)        = rV0;
    *(f16x8*)(VtL + (keyA + 32) * KROW + off8 * 2) = rV1;
    __syncthreads();

    // ---- scores^T (exp2 domain; scale folded into Q), single product ----
    f32x16 s0, s1;
#pragma unroll
    for (int r = 0; r < 16; ++r) { s0[r] = 0.f; s1[r] = 0.f; }
#pragma unroll
    for (int t = 0; t < 4; ++t) {
      f16x8 a0 = *(const f16x8*)(KL + l31 * KROW + 32 * t + 16 * h5);
      f16x8 a1 = *(const f16x8*)(KL + (32 + l31) * KROW + 32 * t + 16 * h5);
      s0 = __builtin_amdgcn_mfma_f32_32x32x16_f16(a0, qf[t], s0, 0, 0, 0);
      s1 = __builtin_amdgcn_mfma_f32_32x32x16_f16(a1, qf[t], s1, 0, 0, 0);
    }

    // ---- online softmax (exp2 domain) with defer-max ----
    float tmax = s0[0];
#pragma unroll
    for (int r = 1; r < 16; ++r) tmax = fmaxf(tmax, s0[r]);
#pragma unroll
    for (int r = 0; r < 16; ++r) tmax = fmaxf(tmax, s1[r]);
    tmax = fmaxf(tmax, __shfl_xor(tmax, 32));
    if (!__all(tmax - m <= 8.0f)) {
      const float mn = fmaxf(m, tmax);
      const float fr = exp2f(m - mn);
      lsum *= fr;
#pragma unroll
      for (int r = 0; r < 16; ++r) { o0[r] *= fr; o1[r] *= fr; }
      m = mn;
    }
    float ts = 0.f;
#pragma unroll
    for (int r = 0; r < 16; ++r) { s0[r] = exp2f(s0[r] - m); ts += s0[r]; }
#pragma unroll
    for (int r = 0; r < 16; ++r) { s1[r] = exp2f(s1[r] - m); ts += s1[r]; }
    ts += __shfl_xor(ts, 32);
    lsum += ts;

    pv_step(s0, 0);
    pv_step(s1, 64);
  }

  // ---- epilogue: O^T -> LDS transpose -> coalesced f16 stores ----
  __syncthreads();
  const float inv = 1.f / lsum;
  float* owp = Ow + w * 32 * OWST;
#pragma unroll
  for (int r = 0; r < 16; ++r) {
    const int d = (r & 3) + 8 * (r >> 2) + 4 * h5;
    owp[l31 * OWST + d]      = o0[r] * inv;
    owp[l31 * OWST + d + 32] = o1[r] * inv;
  }
  __syncthreads();
#pragma unroll
  for (int it = 0; it < 8; ++it) {
    const int row = it * 4 + (lane >> 4);
    const int col = (lane & 15) * 4;
    float4 val = *(float4*)(owp + row * OWST + col);
    const int token = b * S + qt * 128 + w * 32 + row;
    f16x4 hv;
    hv[0] = (f16)val.x; hv[1] = (f16)val.y; hv[2] = (f16)val.z; hv[3] = (f16)val.w;
    *(f16x4*)(Cc + (size_t)token * D + h * 64 + col) = hv;
  }
}

// ---------------------------------------------------------------------------

extern "C" void kernel_launch(void* const* d_in, const int* in_sizes, int n_in,
                              void* d_out, int out_size, void* d_ws, size_t ws_size,
                              hipStream_t stream) {
  const float* X  = (const float*)d_in[0];
  const float* Wq = (const float*)d_in[1];
  const float* bq = (const float*)d_in[2];
  const float* Wk = (const float*)d_in[3];
  const float* bk = (const float*)d_in[4];
  const float* Wv = (const float*)d_in[5];
  const float* bv = (const float*)d_in[6];
  const float* Wo = (const float*)d_in[7];
  const float* bo = (const float*)d_in[8];
  float* out = (float*)d_out;

  const int B = 2, S = 2048, D = 1024;
  const int M = B * S;                 // 4096
  const size_t MD = (size_t)M * D;     // 4M elements

  f16* Xh  = (f16*)d_ws;               // 8 MB each MD-sized buffer
  f16* Qh  = Xh + MD;
  f16* Kh  = Qh + MD;
  f16* Vtg = Kh + MD;
  f16* Cc  = Vtg + MD;
  f16* Wt  = Cc + MD;                  // 4 x D*D f16 = 8 MB
  f16 *Wts[4];
  for (int i = 0; i < 4; ++i) Wts[i] = Wt + (size_t)i * D * D;

  to_f16_kernel<<<dim3(MD / (256 * 8)), 256, 0, stream>>>(X, Xh);
  tconv_kernel<<<dim3(D / 32, D / 32, 4), 256, 0, stream>>>(
      Wq, Wk, Wv, Wo, Wts[0], Wts[1], Wts[2], Wts[3], D, D);

  gemm_qkv_f16<<<dim3(D / 128, M / 128, 3), 256, 0, stream>>>(
      Xh, Wts[0], Wts[1], Wts[2], bq, bk, bv, Qh, Kh, Vtg, M, D, D);

  flash_f16_kernel<<<dim3(16, 32), 256, 0, stream>>>(Qh, Kh, Vtg, Cc);

  gemm_out_f16<<<dim3(D / 128, M / 128, 1), 256, 0, stream>>>(
      Cc, Wts[3], bo, out, M, D, D);
}